// Round 7
// baseline (447.459 us; speedup 1.0000x reference)
//
#include <hip/hip_runtime.h>
#include <math.h>
#include <float.h>
#include <limits.h>

#define BN      32768   // B*N query rows
#define D_IN    1024
#define E_DIM   128
#define CB_N    8192

typedef _Float16 f16x8 __attribute__((ext_vector_type(8)));
typedef _Float16 f16x4 __attribute__((ext_vector_type(4)));
typedef float    f32x4 __attribute__((ext_vector_type(4)));

// Workspace:
//   ph  : [CB_N/16][4][64][8] f16   2 MB  (ncb*256 hi, B-frag packed)
//   pl  : same                      2 MB
//   rph : [32*8][64][8] f16         0.25 MB (rp*64 hi, B-frag packed)
//   rpl : same                      0.25 MB

// ---------------------------------------------------------------------------
// Kernel 1: merged packs (validated rounds 5-6).
// ---------------------------------------------------------------------------
__global__ __launch_bounds__(256) void pack_kernel(
    const float* __restrict__ cb, const float* __restrict__ rp,
    _Float16* __restrict__ ph, _Float16* __restrict__ pl,
    _Float16* __restrict__ rph, _Float16* __restrict__ rpl) {
    const int t = threadIdx.x;
    if (blockIdx.x < 512) {
        __shared__ float L[16][129];
        const int g = blockIdx.x;
        const int c = t >> 4, p = t & 15;
        const float4 v0 = *(const float4*)&cb[(size_t)(g * 16 + c) * E_DIM + p * 8];
        const float4 v1 = *(const float4*)&cb[(size_t)(g * 16 + c) * E_DIM + p * 8 + 4];
        float ss = v0.x * v0.x + v0.y * v0.y + v0.z * v0.z + v0.w * v0.w
                 + v1.x * v1.x + v1.y * v1.y + v1.z * v1.z + v1.w * v1.w;
#pragma unroll
        for (int m = 1; m < 16; m <<= 1) ss += __shfl_xor(ss, m);
        const float inv = 256.0f / fmaxf(sqrtf(ss), 1e-12f);

        L[c][p * 8 + 0] = v0.x * inv; L[c][p * 8 + 1] = v0.y * inv;
        L[c][p * 8 + 2] = v0.z * inv; L[c][p * 8 + 3] = v0.w * inv;
        L[c][p * 8 + 4] = v1.x * inv; L[c][p * 8 + 5] = v1.y * inv;
        L[c][p * 8 + 6] = v1.z * inv; L[c][p * 8 + 7] = v1.w * inv;
        __syncthreads();

        const int kb = t >> 6, lane = t & 63;
        const int quad = (lane >> 4), col = lane & 15;
        f16x8 h, l;
#pragma unroll
        for (int j = 0; j < 8; ++j) {
            const float v = L[col][kb * 32 + quad * 8 + j];
            const _Float16 hv = (_Float16)v;
            h[j] = hv;
            l[j] = (_Float16)(v - (float)hv);
        }
        const size_t off = ((size_t)(g * 4 + kb) * 64 + lane) * 8;
        *(f16x8*)&ph[off] = h;
        *(f16x8*)&pl[off] = l;
    } else {
        const int w = t >> 6, lane = t & 63;
        const int b = (blockIdx.x - 512) * 4 + w;      // 0..255
        const int kb = b >> 3, nt = b & 7;
        const int quad = lane >> 4, col = lane & 15;
        f16x8 h, l;
#pragma unroll
        for (int j = 0; j < 8; ++j) {
            const float v = rp[(size_t)(kb * 32 + quad * 8 + j) * E_DIM + nt * 16 + col] * 64.0f;
            const _Float16 hv = (_Float16)v;
            h[j] = hv;
            l[j] = (_Float16)(v - (float)hv);
        }
        const size_t off = ((size_t)b * 64 + lane) * 8;
        *(f16x8*)&rph[off] = h;
        *(f16x8*)&rpl[off] = l;
    }
}

// ---------------------------------------------------------------------------
// Kernel 2: FUSED proj + scores + argmax. 32 queries/block, grid 1024.
// __launch_bounds__(256,3): target 3 waves/SIMD (12 waves/CU) for stall cover.
// Phase 1: proj for 32 rows (2 m-tiles/wave, wave owns 32 cols).
// Phase 2: each wave: 32 q (2 chains) x quarter of codes, B register-dbuf,
// sched_barrier pins prefetch issue above the MFMA block.
// LDS: phases alias one 17 KB region (barrier-separated).
// ---------------------------------------------------------------------------
#define PAD_ROW 40    // phase-1 staging row stride (halfwords)
#define PPITCH  132   // handoff row pitch (dwords)

__global__ __launch_bounds__(256, 3) void fused_kernel(
    const float* __restrict__ x,
    const _Float16* __restrict__ rph, const _Float16* __restrict__ rpl,
    const _Float16* __restrict__ ph, const _Float16* __restrict__ pl,
    int* __restrict__ out) {
    __shared__ __align__(16) unsigned char smem[17408];
    _Float16* Ah = (_Float16*)smem;               // phase1: [32][40] f16 2.5 KB
    _Float16* Al = (_Float16*)(smem + 2560);      // phase1: 2.5 KB
    float*    P  = (float*)smem;                  // handoff: [32][132] f32 16.9 KB
    float*    ls = (float*)smem;                  // reduce: [4][32] f32
    int*      li = (int*)(smem + 512);            // reduce: [4][32] int

    const int tid  = threadIdx.x;
    const int lane = tid & 63;
    const int w    = tid >> 6;
    const int quad = lane >> 4, col = lane & 15;
    const int qb   = blockIdx.x * 32;

    // ======================= Phase 1: projection =======================
    const int srow = tid >> 3;        // 0..31
    const int skc  = (tid & 7) * 4;   // 0,4,..,28

    f32x4 acc[2][2];
#pragma unroll
    for (int mt = 0; mt < 2; ++mt)
#pragma unroll
        for (int h = 0; h < 2; ++h) acc[mt][h] = (f32x4){0.f, 0.f, 0.f, 0.f};

    float4 pre = *(const float4*)&x[(size_t)(qb + srow) * D_IN + skc];

    for (int kb = 0; kb < 32; ++kb) {
        {
            const float vv[4] = {pre.x, pre.y, pre.z, pre.w};
            f16x4 h4, l4;
#pragma unroll
            for (int j = 0; j < 4; ++j) {
                const float v = vv[j] * 512.0f;
                const _Float16 hv = (_Float16)v;
                h4[j] = hv;
                l4[j] = (_Float16)(v - (float)hv);
            }
            const int base = srow * PAD_ROW + skc;
            *(f16x4*)&Ah[base] = h4;
            *(f16x4*)&Al[base] = l4;
        }
        __syncthreads();

        if (kb + 1 < 32)
            pre = *(const float4*)&x[(size_t)(qb + srow) * D_IN + (kb + 1) * 32 + skc];

        f16x8 bh1[2], bl1[2];
#pragma unroll
        for (int h = 0; h < 2; ++h) {
            const int nt = w * 2 + h;
            const size_t off = ((size_t)(kb * 8 + nt) * 64 + lane) * 8;
            bh1[h] = *(const f16x8*)&rph[off];
            bl1[h] = *(const f16x8*)&rpl[off];
        }

        f16x8 ah1[2], al1[2];
#pragma unroll
        for (int mt = 0; mt < 2; ++mt) {
            const int base = (mt * 16 + col) * PAD_ROW + quad * 8;
            ah1[mt] = *(const f16x8*)&Ah[base];
            al1[mt] = *(const f16x8*)&Al[base];
        }

#pragma unroll
        for (int mt = 0; mt < 2; ++mt)
#pragma unroll
            for (int h = 0; h < 2; ++h)
                acc[mt][h] = __builtin_amdgcn_mfma_f32_16x16x32_f16(ah1[mt], bh1[h], acc[mt][h], 0, 0, 0);
#pragma unroll
        for (int mt = 0; mt < 2; ++mt)
#pragma unroll
            for (int h = 0; h < 2; ++h)
                acc[mt][h] = __builtin_amdgcn_mfma_f32_16x16x32_f16(ah1[mt], bl1[h], acc[mt][h], 0, 0, 0);
#pragma unroll
        for (int mt = 0; mt < 2; ++mt)
#pragma unroll
            for (int h = 0; h < 2; ++h)
                acc[mt][h] = __builtin_amdgcn_mfma_f32_16x16x32_f16(al1[mt], bh1[h], acc[mt][h], 0, 0, 0);

        __syncthreads();
    }

    // Write proj*16 (f32) to LDS P [32 q][128 k] (aliases Ah/Al; last reads done).
#pragma unroll
    for (int mt = 0; mt < 2; ++mt)
#pragma unroll
        for (int h = 0; h < 2; ++h)
#pragma unroll
            for (int r = 0; r < 4; ++r)
                P[(mt * 16 + quad * 4 + r) * PPITCH + w * 32 + h * 16 + col]
                    = acc[mt][h][r] * (1.0f / 2048.0f);

    // Prefetch B tile 0 of this wave's code quarter (global; overlaps barrier).
    const int g0 = w * 128;   // 128 16-code tiles per wave (2048 codes)
    f16x8 bh[2][4], bl[2][4];
#pragma unroll
    for (int kb = 0; kb < 4; ++kb) {
        const size_t off = ((size_t)(g0 * 4 + kb) * 64 + lane) * 8;
        bh[0][kb] = *(const f16x8*)&ph[off];
        bl[0][kb] = *(const f16x8*)&pl[off];
    }
    __syncthreads();

    // ============ Handoff: wave reads A-frags for all 32 queries ============
    f16x8 ahF[2][4], alF[2][4];
#pragma unroll
    for (int mt2 = 0; mt2 < 2; ++mt2)
#pragma unroll
        for (int kbb = 0; kbb < 4; ++kbb) {
            const int base = (mt2 * 16 + col) * PPITCH + kbb * 32 + quad * 8;
            const float4 v0 = *(const float4*)&P[base];
            const float4 v1 = *(const float4*)&P[base + 4];
            const float vv[8] = {v0.x, v0.y, v0.z, v0.w, v1.x, v1.y, v1.z, v1.w};
            f16x8 hh, ll;
#pragma unroll
            for (int j = 0; j < 8; ++j) {
                const _Float16 hv = (_Float16)vv[j];
                hh[j] = hv;
                ll[j] = (_Float16)(vv[j] - (float)hv);
            }
            ahF[mt2][kbb] = hh;
            alF[mt2][kbb] = ll;
        }

    // ======================= Phase 2: scores + argmax =======================
    float bs[8];
    int   bi[8];
#pragma unroll
    for (int s = 0; s < 8; ++s) { bs[s] = -FLT_MAX; bi[s] = 0; }

#pragma unroll 2
    for (int t = 0; t < 128; ++t) {
        const int cur = t & 1, nxt = cur ^ 1;
        if (t + 1 < 128) {
            const int gn = g0 + t + 1;
#pragma unroll
            for (int kb = 0; kb < 4; ++kb) {
                const size_t off = ((size_t)(gn * 4 + kb) * 64 + lane) * 8;
                bh[nxt][kb] = *(const f16x8*)&ph[off];
                bl[nxt][kb] = *(const f16x8*)&pl[off];
            }
        }
        // Pin: prefetch issues stay ABOVE the MFMA block (don't let the
        // scheduler sink them to their use site).
        __builtin_amdgcn_sched_barrier(0);

        f32x4 s0 = (f32x4){0.f, 0.f, 0.f, 0.f};
        f32x4 s1 = (f32x4){0.f, 0.f, 0.f, 0.f};
#pragma unroll
        for (int kb = 0; kb < 4; ++kb) {
            s0 = __builtin_amdgcn_mfma_f32_16x16x32_f16(ahF[0][kb], bh[cur][kb], s0, 0, 0, 0);
            s1 = __builtin_amdgcn_mfma_f32_16x16x32_f16(ahF[1][kb], bh[cur][kb], s1, 0, 0, 0);
        }
#pragma unroll
        for (int kb = 0; kb < 4; ++kb) {
            s0 = __builtin_amdgcn_mfma_f32_16x16x32_f16(ahF[0][kb], bl[cur][kb], s0, 0, 0, 0);
            s1 = __builtin_amdgcn_mfma_f32_16x16x32_f16(ahF[1][kb], bl[cur][kb], s1, 0, 0, 0);
        }
#pragma unroll
        for (int kb = 0; kb < 4; ++kb) {
            s0 = __builtin_amdgcn_mfma_f32_16x16x32_f16(alF[0][kb], bh[cur][kb], s0, 0, 0, 0);
            s1 = __builtin_amdgcn_mfma_f32_16x16x32_f16(alF[1][kb], bh[cur][kb], s1, 0, 0, 0);
        }

        const int code = (g0 + t) * 16 + col;
#pragma unroll
        for (int r = 0; r < 4; ++r) {
            if (s0[r] > bs[r])     { bs[r] = s0[r];     bi[r] = code; }      // ascending: > keeps min idx
            if (s1[r] > bs[4 + r]) { bs[4 + r] = s1[r]; bi[4 + r] = code; }
        }
    }

    // Reduce 16 code-columns per query (xor over low 4 lane bits).
#pragma unroll
    for (int s = 0; s < 8; ++s) {
#pragma unroll
        for (int m = 1; m < 16; m <<= 1) {
            const float os = __shfl_xor(bs[s], m);
            const int   oi = __shfl_xor(bi[s], m);
            if (os > bs[s] || (os == bs[s] && oi < bi[s])) { bs[s] = os; bi[s] = oi; }
        }
    }

    if (col == 0) {
#pragma unroll
        for (int mt2 = 0; mt2 < 2; ++mt2)
#pragma unroll
            for (int r = 0; r < 4; ++r) {
                ls[w * 32 + mt2 * 16 + quad * 4 + r] = bs[mt2 * 4 + r];
                li[w * 32 + mt2 * 16 + quad * 4 + r] = bi[mt2 * 4 + r];
            }
    }
    __syncthreads();

    // 4-way cross-wave merge (code ranges ascending in w: > keeps min idx).
    if (tid < 32) {
        float s = ls[tid];
        int   i = li[tid];
#pragma unroll
        for (int ww = 1; ww < 4; ++ww) {
            const float os = ls[ww * 32 + tid];
            if (os > s) { s = os; i = li[ww * 32 + tid]; }
        }
        out[qb + tid] = i;
    }
}

// ---------------------------------------------------------------------------
extern "C" void kernel_launch(void* const* d_in, const int* in_sizes, int n_in,
                              void* d_out, int out_size, void* d_ws, size_t ws_size,
                              hipStream_t stream) {
    const float* x  = (const float*)d_in[0];   // [8,4096,1024]
    const float* rp = (const float*)d_in[1];   // [1024,128]
    const float* cb = (const float*)d_in[2];   // [8192,128]
    int* out = (int*)d_out;                    // [8,4096] int32

    _Float16* ph  = (_Float16*)d_ws;                         // 2 MB
    _Float16* pl  = ph  + (size_t)CB_N * E_DIM;              // 2 MB
    _Float16* rph = pl  + (size_t)CB_N * E_DIM;              // 256 KB
    _Float16* rpl = rph + (size_t)D_IN * E_DIM;              // 256 KB

    pack_kernel<<<576, 256, 0, stream>>>(cb, rp, ph, pl, rph, rpl);
    fused_kernel<<<BN / 32, 256, 0, stream>>>(x, rph, rpl, ph, pl, out);
}

// Round 8
// 402.665 us; speedup vs baseline: 1.1112x; 1.1112x over previous
//
#include <hip/hip_runtime.h>
#include <math.h>
#include <float.h>
#include <limits.h>

#define BN      32768   // B*N query rows
#define D_IN    1024
#define E_DIM   128
#define CB_N    8192

typedef _Float16 f16x8 __attribute__((ext_vector_type(8)));
typedef _Float16 f16x4 __attribute__((ext_vector_type(4)));
typedef float    f32x4 __attribute__((ext_vector_type(4)));

// Workspace:
//   ph  : [CB_N/16][4][64][8] f16   2 MB  (ncb*256 hi, B-frag packed)
//   pl  : same                      2 MB
//   rph : [32*8][64][8] f16         0.25 MB (rp*64 hi, B-frag packed)
//   rpl : same                      0.25 MB

// ---------------------------------------------------------------------------
// Kernel 1: merged packs (validated rounds 5-7).
// ---------------------------------------------------------------------------
__global__ __launch_bounds__(256) void pack_kernel(
    const float* __restrict__ cb, const float* __restrict__ rp,
    _Float16* __restrict__ ph, _Float16* __restrict__ pl,
    _Float16* __restrict__ rph, _Float16* __restrict__ rpl) {
    const int t = threadIdx.x;
    if (blockIdx.x < 512) {
        __shared__ float L[16][129];
        const int g = blockIdx.x;
        const int c = t >> 4, p = t & 15;
        const float4 v0 = *(const float4*)&cb[(size_t)(g * 16 + c) * E_DIM + p * 8];
        const float4 v1 = *(const float4*)&cb[(size_t)(g * 16 + c) * E_DIM + p * 8 + 4];
        float ss = v0.x * v0.x + v0.y * v0.y + v0.z * v0.z + v0.w * v0.w
                 + v1.x * v1.x + v1.y * v1.y + v1.z * v1.z + v1.w * v1.w;
#pragma unroll
        for (int m = 1; m < 16; m <<= 1) ss += __shfl_xor(ss, m);
        const float inv = 256.0f / fmaxf(sqrtf(ss), 1e-12f);

        L[c][p * 8 + 0] = v0.x * inv; L[c][p * 8 + 1] = v0.y * inv;
        L[c][p * 8 + 2] = v0.z * inv; L[c][p * 8 + 3] = v0.w * inv;
        L[c][p * 8 + 4] = v1.x * inv; L[c][p * 8 + 5] = v1.y * inv;
        L[c][p * 8 + 6] = v1.z * inv; L[c][p * 8 + 7] = v1.w * inv;
        __syncthreads();

        const int kb = t >> 6, lane = t & 63;
        const int quad = (lane >> 4), col = lane & 15;
        f16x8 h, l;
#pragma unroll
        for (int j = 0; j < 8; ++j) {
            const float v = L[col][kb * 32 + quad * 8 + j];
            const _Float16 hv = (_Float16)v;
            h[j] = hv;
            l[j] = (_Float16)(v - (float)hv);
        }
        const size_t off = ((size_t)(g * 4 + kb) * 64 + lane) * 8;
        *(f16x8*)&ph[off] = h;
        *(f16x8*)&pl[off] = l;
    } else {
        const int w = t >> 6, lane = t & 63;
        const int b = (blockIdx.x - 512) * 4 + w;      // 0..255
        const int kb = b >> 3, nt = b & 7;
        const int quad = lane >> 4, col = lane & 15;
        f16x8 h, l;
#pragma unroll
        for (int j = 0; j < 8; ++j) {
            const float v = rp[(size_t)(kb * 32 + quad * 8 + j) * E_DIM + nt * 16 + col] * 64.0f;
            const _Float16 hv = (_Float16)v;
            h[j] = hv;
            l[j] = (_Float16)(v - (float)hv);
        }
        const size_t off = ((size_t)b * 64 + lane) * 8;
        *(f16x8*)&rph[off] = h;
        *(f16x8*)&rpl[off] = l;
    }
}

// ---------------------------------------------------------------------------
// Kernel 2: FUSED proj + scores + argmax — round-4 structure (best measured:
// 255 us, VGPR 100, no spill) with ONE change: phase-2 accumulators split per
// pass (hi*hi / hi*lo / lo*hi) -> 6 independent MFMA chains (dep gap 6 issues
// > MFMA latency) instead of 2 (gap 2, latency-bound at 43% MfmaUtil).
// 64 queries/block, grid 512 (2 blocks/CU). Wave = (query half, code half).
// ---------------------------------------------------------------------------
#define PAD_ROW 40    // phase-1 staging row stride (halfwords)
#define PPITCH  132   // phase-2 proj buffer row pitch (dwords)

__global__ __launch_bounds__(256, 2) void fused_kernel(
    const float* __restrict__ x,
    const _Float16* __restrict__ rph, const _Float16* __restrict__ rpl,
    const _Float16* __restrict__ ph, const _Float16* __restrict__ pl,
    int* __restrict__ out) {
    __shared__ _Float16 Ah[64 * PAD_ROW];
    __shared__ _Float16 Al[64 * PAD_ROW];
    __shared__ float    P[64 * PPITCH];
    __shared__ float    ls[4][32];
    __shared__ int      li[4][32];

    const int tid  = threadIdx.x;
    const int lane = tid & 63;
    const int w    = tid >> 6;
    const int quad = lane >> 4, col = lane & 15;
    const int qb   = blockIdx.x * 64;

    // ======================= Phase 1: projection =======================
    const int srow = tid >> 3;        // 0..31
    const int skc  = (tid & 7) * 4;   // 0,4,..,28

    f32x4 acc[4][2];
#pragma unroll
    for (int mt = 0; mt < 4; ++mt)
#pragma unroll
        for (int h = 0; h < 2; ++h) acc[mt][h] = (f32x4){0.f, 0.f, 0.f, 0.f};

    float4 pre[2];
#pragma unroll
    for (int i = 0; i < 2; ++i)
        pre[i] = *(const float4*)&x[(size_t)(qb + srow + 32 * i) * D_IN + skc];

    for (int kb = 0; kb < 32; ++kb) {
#pragma unroll
        for (int i = 0; i < 2; ++i) {
            const float vv[4] = {pre[i].x, pre[i].y, pre[i].z, pre[i].w};
            f16x4 h4, l4;
#pragma unroll
            for (int j = 0; j < 4; ++j) {
                const float v = vv[j] * 512.0f;
                const _Float16 hv = (_Float16)v;
                h4[j] = hv;
                l4[j] = (_Float16)(v - (float)hv);
            }
            const int base = (srow + 32 * i) * PAD_ROW + skc;
            *(f16x4*)&Ah[base] = h4;
            *(f16x4*)&Al[base] = l4;
        }
        __syncthreads();

        if (kb + 1 < 32) {
#pragma unroll
            for (int i = 0; i < 2; ++i)
                pre[i] = *(const float4*)&x[(size_t)(qb + srow + 32 * i) * D_IN + (kb + 1) * 32 + skc];
        }

        f16x8 bh1[2], bl1[2];
#pragma unroll
        for (int h = 0; h < 2; ++h) {
            const int nt = w * 2 + h;
            const size_t off = ((size_t)(kb * 8 + nt) * 64 + lane) * 8;
            bh1[h] = *(const f16x8*)&rph[off];
            bl1[h] = *(const f16x8*)&rpl[off];
        }

        f16x8 ah1[4], al1[4];
#pragma unroll
        for (int mt = 0; mt < 4; ++mt) {
            const int base = (mt * 16 + col) * PAD_ROW + quad * 8;
            ah1[mt] = *(const f16x8*)&Ah[base];
            al1[mt] = *(const f16x8*)&Al[base];
        }

#pragma unroll
        for (int mt = 0; mt < 4; ++mt)
#pragma unroll
            for (int h = 0; h < 2; ++h)
                acc[mt][h] = __builtin_amdgcn_mfma_f32_16x16x32_f16(ah1[mt], bh1[h], acc[mt][h], 0, 0, 0);
#pragma unroll
        for (int mt = 0; mt < 4; ++mt)
#pragma unroll
            for (int h = 0; h < 2; ++h)
                acc[mt][h] = __builtin_amdgcn_mfma_f32_16x16x32_f16(ah1[mt], bl1[h], acc[mt][h], 0, 0, 0);
#pragma unroll
        for (int mt = 0; mt < 4; ++mt)
#pragma unroll
            for (int h = 0; h < 2; ++h)
                acc[mt][h] = __builtin_amdgcn_mfma_f32_16x16x32_f16(al1[mt], bh1[h], acc[mt][h], 0, 0, 0);

        __syncthreads();
    }

    // Write proj*16 (f32) to LDS transpose buffer [query][k].
#pragma unroll
    for (int mt = 0; mt < 4; ++mt)
#pragma unroll
        for (int h = 0; h < 2; ++h)
#pragma unroll
            for (int r = 0; r < 4; ++r) {
                const int row = mt * 16 + quad * 4 + r;
                const int cc  = w * 32 + h * 16 + col;
                P[row * PPITCH + cc] = acc[mt][h][r] * (1.0f / 2048.0f);
            }
    __syncthreads();

    // ======================= Phase 2: scores + argmax =======================
    const int wq = w >> 1;   // query half: m-tiles wq*2, wq*2+1
    const int wc = w & 1;    // code half: tiles [wc*256, wc*256+256)

    // A frags from LDS: A[m=col][k=quad*8+j], split hi/lo.
    f16x8 ah[2][4], al[2][4];
#pragma unroll
    for (int mt2 = 0; mt2 < 2; ++mt2)
#pragma unroll
        for (int kb = 0; kb < 4; ++kb) {
            const int base = (wq * 32 + mt2 * 16 + col) * PPITCH + kb * 32 + quad * 8;
            const float4 v0 = *(const float4*)&P[base];
            const float4 v1 = *(const float4*)&P[base + 4];
            const float vv[8] = {v0.x, v0.y, v0.z, v0.w, v1.x, v1.y, v1.z, v1.w};
            f16x8 hh, ll;
#pragma unroll
            for (int j = 0; j < 8; ++j) {
                const _Float16 hv = (_Float16)vv[j];
                hh[j] = hv;
                ll[j] = (_Float16)(vv[j] - (float)hv);
            }
            ah[mt2][kb] = hh;
            al[mt2][kb] = ll;
        }

    float bs[8];
    int   bi[8];
#pragma unroll
    for (int s = 0; s < 8; ++s) { bs[s] = -FLT_MAX; bi[s] = 0; }

    const int g0 = wc * 256;

    // B double buffer in registers.
    f16x8 bh[2][4], bl[2][4];
#pragma unroll
    for (int kb = 0; kb < 4; ++kb) {
        const size_t off = ((size_t)(g0 * 4 + kb) * 64 + lane) * 8;
        bh[0][kb] = *(const f16x8*)&ph[off];
        bl[0][kb] = *(const f16x8*)&pl[off];
    }

#pragma unroll 2
    for (int t = 0; t < 256; ++t) {
        const int cur = t & 1, nxt = cur ^ 1;
        if (t + 1 < 256) {
            const int gn = g0 + t + 1;
#pragma unroll
            for (int kb = 0; kb < 4; ++kb) {
                const size_t off = ((size_t)(gn * 4 + kb) * 64 + lane) * 8;
                bh[nxt][kb] = *(const f16x8*)&ph[off];
                bl[nxt][kb] = *(const f16x8*)&pl[off];
            }
        }

        // 6 independent accumulator chains: (m-tile 0/1) x (pass hh/hl/lh).
        f32x4 a0h = (f32x4){0.f, 0.f, 0.f, 0.f}, a0m = a0h, a0l = a0h;
        f32x4 a1h = a0h, a1m = a0h, a1l = a0h;

#pragma unroll
        for (int kb = 0; kb < 4; ++kb) {
            a0h = __builtin_amdgcn_mfma_f32_16x16x32_f16(ah[0][kb], bh[cur][kb], a0h, 0, 0, 0);
            a1h = __builtin_amdgcn_mfma_f32_16x16x32_f16(ah[1][kb], bh[cur][kb], a1h, 0, 0, 0);
            a0m = __builtin_amdgcn_mfma_f32_16x16x32_f16(ah[0][kb], bl[cur][kb], a0m, 0, 0, 0);
            a1m = __builtin_amdgcn_mfma_f32_16x16x32_f16(ah[1][kb], bl[cur][kb], a1m, 0, 0, 0);
            a0l = __builtin_amdgcn_mfma_f32_16x16x32_f16(al[0][kb], bh[cur][kb], a0l, 0, 0, 0);
            a1l = __builtin_amdgcn_mfma_f32_16x16x32_f16(al[1][kb], bh[cur][kb], a1l, 0, 0, 0);
        }

        const f32x4 s0 = a0h + a0m + a0l;
        const f32x4 s1 = a1h + a1m + a1l;

        const int code = (g0 + t) * 16 + col;
#pragma unroll
        for (int r = 0; r < 4; ++r) {
            if (s0[r] > bs[r])     { bs[r] = s0[r];     bi[r] = code; }      // ascending: > keeps min idx
            if (s1[r] > bs[4 + r]) { bs[4 + r] = s1[r]; bi[4 + r] = code; }
        }
    }

    // Reduce the 16 code-columns per query (lanes differ in low 4 bits).
#pragma unroll
    for (int s = 0; s < 8; ++s) {
#pragma unroll
        for (int m = 1; m < 16; m <<= 1) {
            const float os = __shfl_xor(bs[s], m);
            const int   oi = __shfl_xor(bi[s], m);
            if (os > bs[s] || (os == bs[s] && oi < bi[s])) { bs[s] = os; bi[s] = oi; }
        }
    }

    if (col == 0) {
#pragma unroll
        for (int mt2 = 0; mt2 < 2; ++mt2)
#pragma unroll
            for (int r = 0; r < 4; ++r) {
                ls[w][mt2 * 16 + quad * 4 + r] = bs[mt2 * 4 + r];
                li[w][mt2 * 16 + quad * 4 + r] = bi[mt2 * 4 + r];
            }
    }
    __syncthreads();

    // Merge the two code halves (wc=0 codes < wc=1 codes: > keeps min idx).
    if (tid < 64) {
        const int q   = tid;
        const int wq2 = q >> 5;
        const int q32 = q & 31;
        float s = ls[wq2 * 2 + 0][q32];
        int   i = li[wq2 * 2 + 0][q32];
        const float os = ls[wq2 * 2 + 1][q32];
        if (os > s) { s = os; i = li[wq2 * 2 + 1][q32]; }
        out[qb + q] = i;
    }
}

// ---------------------------------------------------------------------------
extern "C" void kernel_launch(void* const* d_in, const int* in_sizes, int n_in,
                              void* d_out, int out_size, void* d_ws, size_t ws_size,
                              hipStream_t stream) {
    const float* x  = (const float*)d_in[0];   // [8,4096,1024]
    const float* rp = (const float*)d_in[1];   // [1024,128]
    const float* cb = (const float*)d_in[2];   // [8192,128]
    int* out = (int*)d_out;                    // [8,4096] int32

    _Float16* ph  = (_Float16*)d_ws;                         // 2 MB
    _Float16* pl  = ph  + (size_t)CB_N * E_DIM;              // 2 MB
    _Float16* rph = pl  + (size_t)CB_N * E_DIM;              // 256 KB
    _Float16* rpl = rph + (size_t)D_IN * E_DIM;              // 256 KB

    pack_kernel<<<576, 256, 0, stream>>>(cb, rp, ph, pl, rph, rpl);
    fused_kernel<<<BN / 64, 256, 0, stream>>>(x, rph, rpl, ph, pl, out);
}